// Round 3
// baseline (929.648 us; speedup 1.0000x reference)
//
#include <hip/hip_runtime.h>
#include <cstddef>

#define DD 128
#define FAN 8

__device__ __forceinline__ void lds_fence() {
    asm volatile("s_waitcnt lgkmcnt(0)" ::: "memory");
}

// broadcast lane l's value of v to all lanes via v_readlane (VALU, no LDS)
__device__ __forceinline__ float rlane(float v, int l) {
    return __int_as_float(__builtin_amdgcn_readlane(__float_as_int(v), l));
}

// Fused SAGE layer. x = [self | mean(neigh)] (K=256) stays in registers
// (wave-uniform -> readlane broadcast). W = [Ws;Wn] lives in LDS in an
// interleaved row-pair layout so each access is one ds_read_b128:
//   sWv[kp*64 + lane] = {W[2kp][2l], W[2kp][2l+1], W[2kp+1][2l], W[2kp+1][2l+1]}
// 8 waves/block, R rows per wave per group; lane owns output cols 2l,2l+1.
template<bool RELU, int R>
__global__ __launch_bounds__(512, 2)
void sage_kernel(const float* __restrict__ X, const int* __restrict__ es,
                 const float* __restrict__ Ws, const float* __restrict__ Wn,
                 const float* __restrict__ bn, float* __restrict__ Y,
                 int n_groups)
{
    __shared__ float sW[2 * DD * DD];   // 128 KB

    const int tid  = threadIdx.x;
    const int lane = tid & 63;
    const int wave = tid >> 6;

    // stage W interleaved: dst[(k>>1)*256 + l*4 + (k&1)*2 + {0,1}] = W[k][2l..2l+1]
    #pragma unroll
    for (int i = 0; i < 32; ++i) {
        const int idx = i * 512 + tid;          // float2 unit id, 16384 total
        const int k = idx >> 6, l = idx & 63;
        const float2 v = (k < DD)
            ? *((const float2*)(Ws + (size_t)k * DD) + l)
            : *((const float2*)(Wn + (size_t)(k - DD) * DD) + l);
        *(float2*)&sW[(k >> 1) * 256 + l * 4 + (k & 1) * 2] = v;
    }
    __syncthreads();

    const float2 bv = *((const float2*)bn + lane);
    const float4* sWv = (const float4*)sW;

    for (int g = blockIdx.x; g < n_groups; g += gridDim.x) {
        const int row0 = (g * 8 + wave) * R;

        // ---- gather: self + mean of 8 neighbors, into registers ----
        float s0[R], s1[R], m0[R], m1[R];
        #pragma unroll
        for (int rr = 0; rr < R; ++rr) {
            const int r = row0 + rr;
            const int* ep = es + (size_t)r * FAN;
            const float2 sv = *((const float2*)(X + (size_t)r * DD) + lane);
            float g0 = 0.f, g1 = 0.f;
            #pragma unroll
            for (int j = 0; j < FAN; ++j) {
                const float2 v = *((const float2*)(X + (size_t)ep[j] * DD) + lane);
                g0 += v.x; g1 += v.y;
            }
            s0[rr] = sv.x; s1[rr] = sv.y;
            m0[rr] = g0 * 0.125f; m1[rr] = g1 * 0.125f;
        }

        // ---- K=256 dot: W from LDS (b128), x broadcast via readlane ----
        float acc0[R], acc1[R];
        #pragma unroll
        for (int rr = 0; rr < R; ++rr) { acc0[rr] = 0.f; acc1[rr] = 0.f; }

        #pragma unroll 2
        for (int kp = 0; kp < 64; ++kp) {           // self half (Ws)
            const float4 w = sWv[kp * 64 + lane];
            #pragma unroll
            for (int rr = 0; rr < R; ++rr) {
                const float xa = rlane(s0[rr], kp);
                const float xb = rlane(s1[rr], kp);
                acc0[rr] = fmaf(xa, w.x, acc0[rr]);
                acc1[rr] = fmaf(xa, w.y, acc1[rr]);
                acc0[rr] = fmaf(xb, w.z, acc0[rr]);
                acc1[rr] = fmaf(xb, w.w, acc1[rr]);
            }
        }
        #pragma unroll 2
        for (int kp = 64; kp < 128; ++kp) {         // neigh half (Wn)
            const float4 w = sWv[kp * 64 + lane];
            #pragma unroll
            for (int rr = 0; rr < R; ++rr) {
                const float xa = rlane(m0[rr], kp - 64);
                const float xb = rlane(m1[rr], kp - 64);
                acc0[rr] = fmaf(xa, w.x, acc0[rr]);
                acc1[rr] = fmaf(xa, w.y, acc1[rr]);
                acc0[rr] = fmaf(xb, w.z, acc0[rr]);
                acc1[rr] = fmaf(xb, w.w, acc1[rr]);
            }
        }

        // ---- epilogue ----
        #pragma unroll
        for (int rr = 0; rr < R; ++rr) {
            const int r = row0 + rr;
            float o0 = acc0[rr] + bv.x;
            float o1 = acc1[rr] + bv.y;
            if (RELU) { o0 = fmaxf(o0, 0.f); o1 = fmaxf(o1, 0.f); }
            *((float2*)(Y + (size_t)r * DD) + lane) = make_float2(o0, o1);
        }
    }
}

// Fused predictor: rows 0..511 -> pos, 512..1023 -> neg.
__global__ __launch_bounds__(512, 2)
void pred_kernel(const float* __restrict__ h3,
                 const float* __restrict__ W1, const float* __restrict__ b1,
                 const float* __restrict__ W2, const float* __restrict__ b2,
                 const float* __restrict__ W3, const float* __restrict__ b3,
                 float* __restrict__ out)
{
    __shared__ float sW1[DD][DD];
    __shared__ float sW2[DD][DD];
    __shared__ float sW3[DD];
    __shared__ float sx[8][4][DD];

    const int tid = threadIdx.x, lane = tid & 63, wave = tid >> 6;
    {
        const float4* a = (const float4*)W1;  float4* d1 = (float4*)&sW1[0][0];
        const float4* c = (const float4*)W2;  float4* d2 = (float4*)&sW2[0][0];
        #pragma unroll
        for (int i = 0; i < 8; ++i) d1[tid + 512 * i] = a[tid + 512 * i];
        #pragma unroll
        for (int i = 0; i < 8; ++i) d2[tid + 512 * i] = c[tid + 512 * i];
        if (tid < DD) sW3[tid] = W3[tid];
    }
    __syncthreads();

    const int row0 = blockIdx.x * 32 + wave * 4;   // 32 blocks * 32 rows = 1024

    #pragma unroll
    for (int rr = 0; rr < 4; ++rr) {
        const int row = row0 + rr;
        const int i = row & 511;
        const int which = row >> 9;                // 0 = pos, 1 = neg
        const float2 a = *((const float2*)(h3 + (size_t)i * DD) + lane);
        const float2 c = *((const float2*)(h3 + (size_t)(512 + which * 512 + i) * DD) + lane);
        *(float2*)&sx[wave][rr][2 * lane] = make_float2(a.x * c.x, a.y * c.y);
    }
    lds_fence();

    float2 t[4];
    #pragma unroll
    for (int rr = 0; rr < 4; ++rr) t[rr] = make_float2(0.f, 0.f);
    #pragma unroll 8
    for (int k = 0; k < DD; k += 2) {
        const float2 w0 = *((const float2*)&sW1[k][0]     + lane);
        const float2 w1 = *((const float2*)&sW1[k + 1][0] + lane);
        #pragma unroll
        for (int rr = 0; rr < 4; ++rr) {
            const float2 xv = *(const float2*)&sx[wave][rr][k];
            t[rr].x = fmaf(xv.x, w0.x, t[rr].x);
            t[rr].y = fmaf(xv.x, w0.y, t[rr].y);
            t[rr].x = fmaf(xv.y, w1.x, t[rr].x);
            t[rr].y = fmaf(xv.y, w1.y, t[rr].y);
        }
    }
    const float2 b1v = *((const float2*)b1 + lane);
    lds_fence();
    #pragma unroll
    for (int rr = 0; rr < 4; ++rr) {
        const float u0 = fmaxf(t[rr].x + b1v.x, 0.f);
        const float u1 = fmaxf(t[rr].y + b1v.y, 0.f);
        *(float2*)&sx[wave][rr][2 * lane] = make_float2(u0, u1);
    }
    lds_fence();

    #pragma unroll
    for (int rr = 0; rr < 4; ++rr) t[rr] = make_float2(0.f, 0.f);
    #pragma unroll 8
    for (int k = 0; k < DD; k += 2) {
        const float2 w0 = *((const float2*)&sW2[k][0]     + lane);
        const float2 w1 = *((const float2*)&sW2[k + 1][0] + lane);
        #pragma unroll
        for (int rr = 0; rr < 4; ++rr) {
            const float2 xv = *(const float2*)&sx[wave][rr][k];
            t[rr].x = fmaf(xv.x, w0.x, t[rr].x);
            t[rr].y = fmaf(xv.x, w0.y, t[rr].y);
            t[rr].x = fmaf(xv.y, w1.x, t[rr].x);
            t[rr].y = fmaf(xv.y, w1.y, t[rr].y);
        }
    }
    const float2 b2v = *((const float2*)b2 + lane);
    const float bias3 = b3[0];

    #pragma unroll
    for (int rr = 0; rr < 4; ++rr) {
        const float u0 = fmaxf(t[rr].x + b2v.x, 0.f);
        const float u1 = fmaxf(t[rr].y + b2v.y, 0.f);
        float p = u0 * sW3[2 * lane] + u1 * sW3[2 * lane + 1];
        #pragma unroll
        for (int off = 32; off > 0; off >>= 1) p += __shfl_down(p, off);
        if (lane == 0) out[row0 + rr] = p + bias3;
    }
}

extern "C" void kernel_launch(void* const* d_in, const int* in_sizes, int n_in,
                              void* d_out, int out_size, void* d_ws, size_t ws_size,
                              hipStream_t stream)
{
    const float* h   = (const float*)d_in[0];
    const int*   es0 = (const int*)d_in[1];
    const int*   es1 = (const int*)d_in[2];
    const int*   es2 = (const int*)d_in[3];
    const float* Ws0 = (const float*)d_in[4];
    const float* Wn0 = (const float*)d_in[5];
    const float* bn0 = (const float*)d_in[6];
    const float* Ws1 = (const float*)d_in[7];
    const float* Wn1 = (const float*)d_in[8];
    const float* bn1 = (const float*)d_in[9];
    const float* Ws2 = (const float*)d_in[10];
    const float* Wn2 = (const float*)d_in[11];
    const float* bn2 = (const float*)d_in[12];
    const float* pW1 = (const float*)d_in[13];
    const float* pb1 = (const float*)d_in[14];
    const float* pW2 = (const float*)d_in[15];
    const float* pb2 = (const float*)d_in[16];
    const float* pW3 = (const float*)d_in[17];
    const float* pb3 = (const float*)d_in[18];
    float* out = (float*)d_out;

    char* ws = (char*)d_ws;
    float* h1 = (float*)(ws);                          // 124416*128*4 = 63,700,992 B
    float* h2 = (float*)(ws + 63700992);               // 13824*128*4  =  7,077,888 B
    float* h3 = (float*)(ws + 63700992 + 7077888);     // 1536*128*4   =    786,432 B

    // rows/group = 8 waves * R; group counts divide exactly:
    // L0: 1944*64 = 124416, L1: 432*32 = 13824, L2: 96*16 = 1536
    sage_kernel<true, 8><<<512, 512, 0, stream>>>(h,  es0, Ws0, Wn0, bn0, h1, 1944);
    sage_kernel<true, 4><<<432, 512, 0, stream>>>(h1, es1, Ws1, Wn1, bn1, h2, 432);
    sage_kernel<false,2><<<96,  512, 0, stream>>>(h2, es2, Ws2, Wn2, bn2, h3, 96);
    pred_kernel<<<32, 512, 0, stream>>>(h3, pW1, pb1, pW2, pb2, pW3, pb3, out);
}